// Round 1
// baseline (3655.748 us; speedup 1.0000x reference)
//
// Round 1: correct fp32 baseline.
// - gemm64: generic 64x64-tile fp32 GEMM (256 thr, 4x4 microtile), epilogues:
//   TANH (encoder L1 / wind L1), BIAS (L2s), U (h=tanh(xWp1+b); u=(1-h^2)*wp2).
//   A-operand composed on the fly: A = X + cxv*V + cxa*Aprev (RK4 stage inputs).
// - accel_g: fused G = U @ Wp1^T with full-row (N=256) blocks, in-block gv/vv
//   row reductions via LDS atomics, writes a = -gv*vs + 0.5*vv*g directly.
// - update_k: RK4 combine + per-row dist^2 vs z_e + running min (wave/row).
// 143 dispatches total. Workspace ~34 MB (A1..A4 overlay the encoder H buffer).

#include <hip/hip_runtime.h>
#include <math.h>

namespace {

constexpr float H_STEP = 1.0f / 15.0f;

__device__ inline float wave_sum(float v) {
#pragma unroll
  for (int off = 32; off > 0; off >>= 1) v += __shfl_xor(v, off);
  return v;
}

enum { EPI_TANH = 0, EPI_BIAS = 1, EPI_U = 2 };

template <int EPI>
__global__ __launch_bounds__(256) void gemm64(
    const float* __restrict__ Ap, const float* __restrict__ Vp,
    const float* __restrict__ Pp, float cxv, float cxa,
    const float* __restrict__ Bm, const float* __restrict__ bias,
    const float* __restrict__ wp2, float* __restrict__ C, int M, int K, int N) {
  __shared__ __align__(16) float As[16][68];  // [k][m], pad 68 -> 16B-aligned rows, 2-way max conflict
  __shared__ __align__(16) float Bs[16][64];  // [k][n]
  const int tid = threadIdx.x;
  const int tx = tid & 15, ty = tid >> 4;
  const int n0 = blockIdx.x * 64;
  const int m0 = blockIdx.y * 64;
  const int ar = tid >> 2, akq = (tid & 3) << 2;  // A tile load: row, k-quad
  const int bk = tid >> 4, bnq = (tid & 15) << 2; // B tile load: k, n-quad

  float acc[4][4] = {};

  for (int k0 = 0; k0 < K; k0 += 16) {
    const size_t aoff = (size_t)(m0 + ar) * K + k0 + akq;
    float4 av = *(const float4*)(Ap + aoff);
    if (Vp) {
      float4 t = *(const float4*)(Vp + aoff);
      av.x += cxv * t.x; av.y += cxv * t.y; av.z += cxv * t.z; av.w += cxv * t.w;
    }
    if (Pp) {
      float4 t = *(const float4*)(Pp + aoff);
      av.x += cxa * t.x; av.y += cxa * t.y; av.z += cxa * t.z; av.w += cxa * t.w;
    }
    float4 bv = *(const float4*)(Bm + (size_t)(k0 + bk) * N + n0 + bnq);
    As[akq + 0][ar] = av.x;
    As[akq + 1][ar] = av.y;
    As[akq + 2][ar] = av.z;
    As[akq + 3][ar] = av.w;
    *(float4*)&Bs[bk][bnq] = bv;
    __syncthreads();
#pragma unroll
    for (int kk = 0; kk < 16; ++kk) {
      const float4 a4 = *(const float4*)&As[kk][ty << 2];
      const float4 b4 = *(const float4*)&Bs[kk][tx << 2];
      const float a[4] = {a4.x, a4.y, a4.z, a4.w};
      const float b[4] = {b4.x, b4.y, b4.z, b4.w};
#pragma unroll
      for (int i = 0; i < 4; ++i)
#pragma unroll
        for (int j = 0; j < 4; ++j) acc[i][j] = fmaf(a[i], b[j], acc[i][j]);
    }
    __syncthreads();
  }

#pragma unroll
  for (int i = 0; i < 4; ++i) {
    const int row = m0 + (ty << 2) + i;
    const int colb = n0 + (tx << 2);
    float o[4];
#pragma unroll
    for (int j = 0; j < 4; ++j) {
      const int col = colb + j;
      float v = acc[i][j] + bias[col];
      if constexpr (EPI == EPI_TANH) {
        v = tanhf(v);
      } else if constexpr (EPI == EPI_U) {
        const float hh = tanhf(v);
        v = (1.0f - hh * hh) * wp2[col];
      }
      o[j] = v;
    }
    float4 o4 = {o[0], o[1], o[2], o[3]};
    *(float4*)(C + (size_t)row * N + colb) = o4;
  }
}

// G = U @ Wp1^T  (G[m,n] = sum_k U[m,k] * Wp1[n,k]), fused accel epilogue:
// vs = V + cva*Aprev; gv=sum_n G*vs; vv=sum_n vs^2; a = -gv*vs + 0.5*vv*G.
// Block: 16 rows x 256 cols (full width), 256 threads, thread tile 4x4.
__global__ __launch_bounds__(256) void accel_g(
    const float* __restrict__ U, const float* __restrict__ Wp1,
    const float* __restrict__ Vb, const float* __restrict__ Pp, float cva,
    float* __restrict__ Aout) {
  __shared__ __align__(16) float As[16][20];   // [k][m]
  __shared__ __align__(16) float Bs[16][256];  // [k][n] = Wp1[n][k]
  __shared__ float gv_s[16], vv_s[16];
  const int tid = threadIdx.x;
  const int m0 = blockIdx.x * 16;
  const int tr = tid >> 6, tc = tid & 63;  // tr uniform per wave
  if (tid < 16) { gv_s[tid] = 0.0f; vv_s[tid] = 0.0f; }
  const int alr = tid >> 4, alk = tid & 15;
  float acc[4][4] = {};

  for (int k0 = 0; k0 < 256; k0 += 16) {
    As[alk][alr] = U[(size_t)(m0 + alr) * 256 + k0 + alk];
    const float* wr = Wp1 + (size_t)tid * 256 + k0;  // row n=tid of Wp1
    const float4 w0 = *(const float4*)(wr + 0);
    const float4 w1 = *(const float4*)(wr + 4);
    const float4 w2 = *(const float4*)(wr + 8);
    const float4 w3 = *(const float4*)(wr + 12);
    Bs[0][tid] = w0.x;  Bs[1][tid] = w0.y;  Bs[2][tid] = w0.z;  Bs[3][tid] = w0.w;
    Bs[4][tid] = w1.x;  Bs[5][tid] = w1.y;  Bs[6][tid] = w1.z;  Bs[7][tid] = w1.w;
    Bs[8][tid] = w2.x;  Bs[9][tid] = w2.y;  Bs[10][tid] = w2.z; Bs[11][tid] = w2.w;
    Bs[12][tid] = w3.x; Bs[13][tid] = w3.y; Bs[14][tid] = w3.z; Bs[15][tid] = w3.w;
    __syncthreads();
#pragma unroll
    for (int kk = 0; kk < 16; ++kk) {
      const float4 a4 = *(const float4*)&As[kk][tr << 2];  // wave-broadcast
      const float4 b4 = *(const float4*)&Bs[kk][tc << 2];
      const float a[4] = {a4.x, a4.y, a4.z, a4.w};
      const float b[4] = {b4.x, b4.y, b4.z, b4.w};
#pragma unroll
      for (int i = 0; i < 4; ++i)
#pragma unroll
        for (int j = 0; j < 4; ++j) acc[i][j] = fmaf(a[i], b[j], acc[i][j]);
    }
    __syncthreads();
  }

  float vs[4][4];
#pragma unroll
  for (int i = 0; i < 4; ++i) {
    const size_t off = (size_t)(m0 + (tr << 2) + i) * 256 + (tc << 2);
    float4 v4 = *(const float4*)(Vb + off);
    if (Pp) {
      const float4 p4 = *(const float4*)(Pp + off);
      v4.x += cva * p4.x; v4.y += cva * p4.y; v4.z += cva * p4.z; v4.w += cva * p4.w;
    }
    vs[i][0] = v4.x; vs[i][1] = v4.y; vs[i][2] = v4.z; vs[i][3] = v4.w;
  }
#pragma unroll
  for (int i = 0; i < 4; ++i) {
    float pgv = 0.0f, pvv = 0.0f;
#pragma unroll
    for (int j = 0; j < 4; ++j) {
      pgv = fmaf(acc[i][j], vs[i][j], pgv);
      pvv = fmaf(vs[i][j], vs[i][j], pvv);
    }
    atomicAdd(&gv_s[(tr << 2) + i], pgv);
    atomicAdd(&vv_s[(tr << 2) + i], pvv);
  }
  __syncthreads();
#pragma unroll
  for (int i = 0; i < 4; ++i) {
    const float gv = gv_s[(tr << 2) + i];
    const float vv = vv_s[(tr << 2) + i];
    const size_t off = (size_t)(m0 + (tr << 2) + i) * 256 + (tc << 2);
    float4 o;
    o.x = -gv * vs[i][0] + 0.5f * vv * acc[i][0];
    o.y = -gv * vs[i][1] + 0.5f * vv * acc[i][1];
    o.z = -gv * vs[i][2] + 0.5f * vv * acc[i][2];
    o.w = -gv * vs[i][3] + 0.5f * vv * acc[i][3];
    *(float4*)(Aout + off) = o;
  }
}

// W_start degenerate-wind fallback + minds init. One wave per row.
__global__ __launch_bounds__(256) void init_fb(float* __restrict__ V,
                                               const float* __restrict__ nr,
                                               float* __restrict__ minds) {
  const int row = blockIdx.x * 4 + (threadIdx.x >> 6);
  const int lane = threadIdx.x & 63;
  const size_t off = (size_t)row * 256 + (lane << 2);
  float4 w = *(const float4*)(V + off);
  float s = w.x * w.x + w.y * w.y + w.z * w.z + w.w * w.w;
  s = wave_sum(s);
  const float wn = sqrtf(s + 1e-24f);
  if (wn < 1e-5f) {  // wave-uniform branch
    const float4 n = *(const float4*)(nr + off);
    float ns = n.x * n.x + n.y * n.y + n.z * n.z + n.w * n.w;
    ns = wave_sum(ns);
    const float nn = sqrtf(ns + 1e-24f);
    const float sc = 1e-4f / (nn + 1e-12f);
    w.x += sc * n.x; w.y += sc * n.y; w.z += sc * n.z; w.w += sc * n.w;
    *(float4*)(V + off) = w;
  }
  if (lane == 0) minds[row] = 3.4e38f;
}

// RK4 combine: xn = x + h v + h^2/6 (a1+a2+a3); vn = v + h/6 (a1+2a2+2a3+a4);
// dist^2(xn, z_e) per row, running min. One wave per row.
__global__ __launch_bounds__(256) void update_k(
    float* __restrict__ X, float* __restrict__ V, const float* __restrict__ A1,
    const float* __restrict__ A2, const float* __restrict__ A3,
    const float* __restrict__ A4, const float* __restrict__ ZE,
    float* __restrict__ minds) {
  const float h = H_STEP;
  const int row = blockIdx.x * 4 + (threadIdx.x >> 6);
  const int lane = threadIdx.x & 63;
  const size_t off = (size_t)row * 256 + (lane << 2);
  const float4 x = *(const float4*)(X + off);
  const float4 v = *(const float4*)(V + off);
  const float4 a1 = *(const float4*)(A1 + off);
  const float4 a2 = *(const float4*)(A2 + off);
  const float4 a3 = *(const float4*)(A3 + off);
  const float4 a4 = *(const float4*)(A4 + off);
  const float4 ze = *(const float4*)(ZE + off);
  const float c1 = h * h / 6.0f, c2 = h / 6.0f;
  float4 xn, vn;
  xn.x = x.x + h * v.x + c1 * (a1.x + a2.x + a3.x);
  xn.y = x.y + h * v.y + c1 * (a1.y + a2.y + a3.y);
  xn.z = x.z + h * v.z + c1 * (a1.z + a2.z + a3.z);
  xn.w = x.w + h * v.w + c1 * (a1.w + a2.w + a3.w);
  vn.x = v.x + c2 * (a1.x + 2.0f * a2.x + 2.0f * a3.x + a4.x);
  vn.y = v.y + c2 * (a1.y + 2.0f * a2.y + 2.0f * a3.y + a4.y);
  vn.z = v.z + c2 * (a1.z + 2.0f * a2.z + 2.0f * a3.z + a4.z);
  vn.w = v.w + c2 * (a1.w + 2.0f * a2.w + 2.0f * a3.w + a4.w);
  *(float4*)(X + off) = xn;
  *(float4*)(V + off) = vn;
  const float dx = xn.x - ze.x, dy = xn.y - ze.y, dz = xn.z - ze.z, dw = xn.w - ze.w;
  float d = dx * dx + dy * dy + dz * dz + dw * dw;
  d = wave_sum(d);
  if (lane == 0) minds[row] = fminf(minds[row], d);
}

__global__ __launch_bounds__(256) void final_mean(const float* __restrict__ minds,
                                                  float* __restrict__ out) {
  __shared__ float wsum[4];
  const int tid = threadIdx.x;
  float s = 0.0f;
  for (int i = tid; i < 4096; i += 256) s += minds[i];
  s = wave_sum(s);
  if ((tid & 63) == 0) wsum[tid >> 6] = s;
  __syncthreads();
  if (tid == 0) out[0] = (wsum[0] + wsum[1] + wsum[2] + wsum[3]) * (1.0f / 4096.0f);
}

}  // namespace

extern "C" void kernel_launch(void* const* d_in, const int* in_sizes, int n_in,
                              void* d_out, int out_size, void* d_ws,
                              size_t ws_size, hipStream_t stream) {
  const float* x_start = (const float*)d_in[0];
  const float* x_end = (const float*)d_in[1];
  const float* noise = (const float*)d_in[2];
  const float* W1 = (const float*)d_in[3];
  const float* b1 = (const float*)d_in[4];
  const float* W2 = (const float*)d_in[5];
  const float* b2 = (const float*)d_in[6];
  const float* Ww1 = (const float*)d_in[7];
  const float* bw1 = (const float*)d_in[8];
  const float* Ww2 = (const float*)d_in[9];
  const float* bw2 = (const float*)d_in[10];
  const float* Wp1 = (const float*)d_in[11];
  const float* bp1 = (const float*)d_in[12];
  const float* wp2 = (const float*)d_in[13];
  float* out = (float*)d_out;

  float* ws = (float*)d_ws;
  const size_t ROWS = 4096, ZN = 256;
  float* Hbuf = ws;                    // 4096*1024 (encoder hidden / wind hidden)
  float* A1 = Hbuf;                    // overlay: A1..A4 reuse Hbuf after wind
  float* A2 = A1 + ROWS * ZN;
  float* A3 = A2 + ROWS * ZN;
  float* A4 = A3 + ROWS * ZN;
  float* X = Hbuf + ROWS * 1024;       // z_s -> position (in-place)
  float* ZE = X + ROWS * ZN;
  float* V = ZE + ROWS * ZN;           // W_start -> velocity (in-place)
  float* U = V + ROWS * ZN;
  float* MINDS = U + ROWS * ZN;

  const dim3 blk(256);
  const float h = H_STEP;

  // encoder: z_s, z_e
  gemm64<EPI_TANH><<<dim3(16, 64), blk, 0, stream>>>(
      x_start, nullptr, nullptr, 0.f, 0.f, W1, b1, nullptr, Hbuf, 4096, 2048, 1024);
  gemm64<EPI_BIAS><<<dim3(4, 64), blk, 0, stream>>>(
      Hbuf, nullptr, nullptr, 0.f, 0.f, W2, b2, nullptr, X, 4096, 1024, 256);
  gemm64<EPI_TANH><<<dim3(16, 64), blk, 0, stream>>>(
      x_end, nullptr, nullptr, 0.f, 0.f, W1, b1, nullptr, Hbuf, 4096, 2048, 1024);
  gemm64<EPI_BIAS><<<dim3(4, 64), blk, 0, stream>>>(
      Hbuf, nullptr, nullptr, 0.f, 0.f, W2, b2, nullptr, ZE, 4096, 1024, 256);
  // wind: V = W_start
  gemm64<EPI_TANH><<<dim3(4, 64), blk, 0, stream>>>(
      X, nullptr, nullptr, 0.f, 0.f, Ww1, bw1, nullptr, Hbuf, 4096, 256, 256);
  gemm64<EPI_BIAS><<<dim3(4, 64), blk, 0, stream>>>(
      Hbuf, nullptr, nullptr, 0.f, 0.f, Ww2, bw2, nullptr, V, 4096, 256, 256);
  init_fb<<<1024, blk, 0, stream>>>(V, noise, MINDS);

  for (int s = 0; s < 15; ++s) {
    // stage 1: XS = x, VS = v
    gemm64<EPI_U><<<dim3(4, 64), blk, 0, stream>>>(
        X, nullptr, nullptr, 0.f, 0.f, Wp1, bp1, wp2, U, 4096, 256, 256);
    accel_g<<<256, blk, 0, stream>>>(U, Wp1, V, nullptr, 0.f, A1);
    // stage 2: XS = x + h/2 v, VS = v + h/2 a1
    gemm64<EPI_U><<<dim3(4, 64), blk, 0, stream>>>(
        X, V, nullptr, 0.5f * h, 0.f, Wp1, bp1, wp2, U, 4096, 256, 256);
    accel_g<<<256, blk, 0, stream>>>(U, Wp1, V, A1, 0.5f * h, A2);
    // stage 3: XS = x + h/2 v + h^2/4 a1, VS = v + h/2 a2
    gemm64<EPI_U><<<dim3(4, 64), blk, 0, stream>>>(
        X, V, A1, 0.5f * h, 0.25f * h * h, Wp1, bp1, wp2, U, 4096, 256, 256);
    accel_g<<<256, blk, 0, stream>>>(U, Wp1, V, A2, 0.5f * h, A3);
    // stage 4: XS = x + h v + h^2/2 a2, VS = v + h a3
    gemm64<EPI_U><<<dim3(4, 64), blk, 0, stream>>>(
        X, V, A2, h, 0.5f * h * h, Wp1, bp1, wp2, U, 4096, 256, 256);
    accel_g<<<256, blk, 0, stream>>>(U, Wp1, V, A3, h, A4);

    update_k<<<1024, blk, 0, stream>>>(X, V, A1, A2, A3, A4, ZE, MINDS);
  }
  final_mean<<<1, blk, 0, stream>>>(MINDS, out);
}

// Round 2
// 498.350 us; speedup vs baseline: 7.3357x; 7.3357x over previous
//
// Round 2: bf16 MFMA everywhere + fully fused persistent trace kernel.
// - gemm_bf16<128,128,EPI>: TN-form MFMA GEMM (A row-major bf16, Bt = B^T
//   row-major bf16), 16x16x32 bf16 MFMA, fp32 accum, epilogues: tanh->bf16,
//   bias->f32, bias->f32+bf16 (dual, for z_s feeding wind MLP).
// - trace_fused: 256 blocks x 16 rows; all 15 RK4 steps in one launch.
//   B-fragments of BOTH Wp1 (matmul2) and Wp1^T (matmul1) live in registers
//   (64 frags = 256 VGPR) for the whole kernel; activations round-trip
//   through LDS (C-layout -> A-layout). State x,v,ap,xacc,vacc in registers
//   at MFMA C/D-owned positions. gv/vv/dist row-reductions: shuffle-xor over
//   l15 + cross-wave LDS. One atomicAdd per block into d_out.

#include <hip/hip_runtime.h>
#include <math.h>

typedef short bf8 __attribute__((ext_vector_type(8)));   // 8 bf16 = 4 VGPR
typedef float f32x4 __attribute__((ext_vector_type(4))); // MFMA acc

namespace {

constexpr float H_STEP = 1.0f / 15.0f;

__device__ inline short f2bf(float f) {  // RNE f32 -> bf16
  unsigned u = __float_as_uint(f);
  u += 0x7fffu + ((u >> 16) & 1u);
  return (short)(u >> 16);
}

__device__ inline float fast_tanh(float x) {
  const float ax = fabsf(x);
  const float e = __expf(-2.0f * ax);
  const float t = (1.0f - e) * __builtin_amdgcn_rcpf(1.0f + e);
  return copysignf(t, x);
}

__device__ inline float wave_sum(float v) {
#pragma unroll
  for (int sh = 32; sh > 0; sh >>= 1) v += __shfl_xor(v, sh);
  return v;
}

// ---------------- converts ----------------

__global__ __launch_bounds__(256) void cvt_r(const float* __restrict__ src,
                                             short* __restrict__ dst, long n) {
  long i = ((long)blockIdx.x * 256 + threadIdx.x) * 4;
  const long stride = (long)gridDim.x * 1024;
  for (; i < n; i += stride) {
    const float4 f = *(const float4*)(src + i);
    ushort4 o;
    o.x = (unsigned short)f2bf(f.x);
    o.y = (unsigned short)f2bf(f.y);
    o.z = (unsigned short)f2bf(f.z);
    o.w = (unsigned short)f2bf(f.w);
    *(ushort4*)(dst + i) = o;
  }
}

// src [K][N] f32 -> dst [N][K] bf16 (transpose + convert)
__global__ __launch_bounds__(256) void cvt_t(const float* __restrict__ src,
                                             short* __restrict__ dst, int K,
                                             int N) {
  __shared__ float tile[32][33];
  const int k0 = blockIdx.y * 32, n0 = blockIdx.x * 32;
  const int tr = threadIdx.x >> 5, tc = threadIdx.x & 31;
#pragma unroll
  for (int i = 0; i < 32; i += 8)
    tile[tr + i][tc] = src[(size_t)(k0 + tr + i) * N + n0 + tc];
  __syncthreads();
#pragma unroll
  for (int i = 0; i < 32; i += 8)
    dst[(size_t)(n0 + tr + i) * K + k0 + tc] = f2bf(tile[tc][tr + i]);
}

// ---------------- bf16 TN GEMM ----------------

enum { EPI_TANH = 0, EPI_F32 = 1, EPI_DUAL = 2 };

template <int BM, int BN, int EPI>
__global__ __launch_bounds__(256) void gemm_bf16(
    const short* __restrict__ A, const short* __restrict__ Bt,
    const float* __restrict__ bias, float* __restrict__ Cf,
    short* __restrict__ Cb, int M, int N, int K) {
  constexpr int MT = BM / 32, NT = BN / 32;
  __shared__ short As[BM * 32];
  __shared__ short Bs[BN * 32];
  const int tid = threadIdx.x;
  const int w = tid >> 6, lane = tid & 63, q = lane >> 4, l15 = lane & 15;
  const int wm = (w >> 1) * (BM / 2), wn = (w & 1) * (BN / 2);
  const int m0 = blockIdx.y * BM, n0 = blockIdx.x * BN;
  const int ldr = tid >> 2, ldk = (tid & 3) * 8;
  const f32x4 fzero = {0.0f, 0.0f, 0.0f, 0.0f};
  f32x4 acc[MT][NT];
#pragma unroll
  for (int mt = 0; mt < MT; ++mt)
#pragma unroll
    for (int nt = 0; nt < NT; ++nt) acc[mt][nt] = fzero;

  for (int k0 = 0; k0 < K; k0 += 32) {
#pragma unroll
    for (int it = 0; it < BM / 64; ++it)
      *(bf8*)&As[(it * 64 + ldr) * 32 + ldk] =
          *(const bf8*)(A + (size_t)(m0 + it * 64 + ldr) * K + k0 + ldk);
#pragma unroll
    for (int it = 0; it < BN / 64; ++it)
      *(bf8*)&Bs[(it * 64 + ldr) * 32 + ldk] =
          *(const bf8*)(Bt + (size_t)(n0 + it * 64 + ldr) * K + k0 + ldk);
    __syncthreads();
    bf8 af[MT], bfr[NT];
#pragma unroll
    for (int mt = 0; mt < MT; ++mt)
      af[mt] = *(const bf8*)&As[(wm + mt * 16 + l15) * 32 + q * 8];
#pragma unroll
    for (int nt = 0; nt < NT; ++nt)
      bfr[nt] = *(const bf8*)&Bs[(wn + nt * 16 + l15) * 32 + q * 8];
#pragma unroll
    for (int mt = 0; mt < MT; ++mt)
#pragma unroll
      for (int nt = 0; nt < NT; ++nt)
        acc[mt][nt] = __builtin_amdgcn_mfma_f32_16x16x32_bf16(
            af[mt], bfr[nt], acc[mt][nt], 0, 0, 0);
    __syncthreads();
  }
#pragma unroll
  for (int mt = 0; mt < MT; ++mt)
#pragma unroll
    for (int nt = 0; nt < NT; ++nt) {
      const int col = n0 + wn + nt * 16 + l15;
      const float bcol = bias[col];
#pragma unroll
      for (int rg = 0; rg < 4; ++rg) {
        const int row = m0 + wm + mt * 16 + q * 4 + rg;
        const float val = acc[mt][nt][rg] + bcol;
        if constexpr (EPI == EPI_TANH) {
          Cb[(size_t)row * N + col] = f2bf(fast_tanh(val));
        } else if constexpr (EPI == EPI_F32) {
          Cf[(size_t)row * N + col] = val;
        } else {
          Cf[(size_t)row * N + col] = val;
          Cb[(size_t)row * N + col] = f2bf(val);
        }
      }
    }
}

// ---------------- W_start fallback ----------------

__global__ __launch_bounds__(256) void init_fb(float* __restrict__ V,
                                               const float* __restrict__ nr) {
  const int row = blockIdx.x * 4 + (threadIdx.x >> 6);
  const int lane = threadIdx.x & 63;
  const size_t off = (size_t)row * 256 + (lane << 2);
  float4 wv = *(const float4*)(V + off);
  float s = wv.x * wv.x + wv.y * wv.y + wv.z * wv.z + wv.w * wv.w;
  s = wave_sum(s);
  const float wn = sqrtf(s + 1e-24f);
  if (wn < 1e-5f) {  // wave-uniform branch
    const float4 n4 = *(const float4*)(nr + off);
    float ns = n4.x * n4.x + n4.y * n4.y + n4.z * n4.z + n4.w * n4.w;
    ns = wave_sum(ns);
    const float nn = sqrtf(ns + 1e-24f);
    const float sc = 1e-4f / (nn + 1e-12f);
    wv.x += sc * n4.x; wv.y += sc * n4.y; wv.z += sc * n4.z; wv.w += sc * n4.w;
    *(float4*)(V + off) = wv;
  }
}

// ---------------- fused trace ----------------
// Block owns 16 rows; thread owns (r = q*4+rg, c = w*64+t*16+l15), the MFMA
// C/D-native positions, so all element-wise state stays in registers.

__global__ __launch_bounds__(256, 1) void trace_fused(
    const float* __restrict__ Xg, const float* __restrict__ Vg,
    const float* __restrict__ ZEg, const short* __restrict__ WT,
    const short* __restrict__ Wp1b, const float* __restrict__ bp1,
    const float* __restrict__ wp2, float* __restrict__ out) {
  constexpr float hs = H_STEP;
  __shared__ short XsL[16 * 264];
  __shared__ short UL[16 * 264];
  __shared__ float gvp[4][16], vvp[4][16], dp[4][16];
  __shared__ float mdL[16];
  const int tid = threadIdx.x;
  const int w = tid >> 6, lane = tid & 63, q = lane >> 4, l15 = lane & 15;
  const int r0 = blockIdx.x * 16;
  const int rb = q * 4;

  // B-fragments of both weight orientations, resident all kernel.
  bf8 B1f[4][8], B2f[4][8];
#pragma unroll
  for (int t = 0; t < 4; ++t) {
    const int n = w * 64 + t * 16 + l15;
#pragma unroll
    for (int ks = 0; ks < 8; ++ks) {
      B1f[t][ks] = *(const bf8*)(WT + n * 256 + ks * 32 + q * 8);    // Wp1^T rows
      B2f[t][ks] = *(const bf8*)(Wp1b + n * 256 + ks * 32 + q * 8);  // Wp1 rows
    }
  }
  float x[4][4], v[4][4], ap[4][4], xacc[4][4], vacc[4][4];
  float bp1c[4], wp2c[4];
#pragma unroll
  for (int t = 0; t < 4; ++t) {
    const int c = w * 64 + t * 16 + l15;
    bp1c[t] = bp1[c];
    wp2c[t] = wp2[c];
#pragma unroll
    for (int rg = 0; rg < 4; ++rg) {
      const size_t off = (size_t)(r0 + rb + rg) * 256 + c;
      x[t][rg] = Xg[off];
      v[t][rg] = Vg[off];
      ap[t][rg] = 0.0f;
      xacc[t][rg] = 0.0f;
      vacc[t][rg] = 0.0f;
    }
  }
  if (tid < 16) mdL[tid] = 3.4e38f;
  const f32x4 fzero = {0.0f, 0.0f, 0.0f, 0.0f};

#pragma unroll 1
  for (int step = 0; step < 15; ++step) {
#pragma unroll
    for (int st = 0; st < 4; ++st) {
      const float cxv = (st == 0) ? 0.0f : (st == 3 ? hs : 0.5f * hs);
      const float cxa =
          (st <= 1) ? 0.0f : (st == 2 ? 0.25f * hs * hs : 0.5f * hs * hs);
      const float cva = (st == 0) ? 0.0f : (st == 3 ? hs : 0.5f * hs);
      // stage position -> LDS (bf16, row-major for A-frags)
#pragma unroll
      for (int t = 0; t < 4; ++t) {
        const int c = w * 64 + t * 16 + l15;
#pragma unroll
        for (int rg = 0; rg < 4; ++rg) {
          const float xs = x[t][rg] + cxv * v[t][rg] + cxa * ap[t][rg];
          XsL[(rb + rg) * 264 + c] = f2bf(xs);
        }
      }
      __syncthreads();
      // matmul1: H = Xs @ Wp1 (cols = hw)
      bf8 af[8];
#pragma unroll
      for (int ks = 0; ks < 8; ++ks)
        af[ks] = *(const bf8*)&XsL[l15 * 264 + ks * 32 + q * 8];
      f32x4 acc[4];
#pragma unroll
      for (int t = 0; t < 4; ++t) {
        acc[t] = fzero;
#pragma unroll
        for (int ks = 0; ks < 8; ++ks)
          acc[t] = __builtin_amdgcn_mfma_f32_16x16x32_bf16(af[ks], B1f[t][ks],
                                                           acc[t], 0, 0, 0);
      }
      // epilogue1: U = (1 - tanh^2) * wp2 -> LDS bf16
#pragma unroll
      for (int t = 0; t < 4; ++t) {
        const int c = w * 64 + t * 16 + l15;
#pragma unroll
        for (int rg = 0; rg < 4; ++rg) {
          const float s = acc[t][rg] + bp1c[t];
          const float th = fast_tanh(s);
          const float u = (1.0f - th * th) * wp2c[t];
          UL[(rb + rg) * 264 + c] = f2bf(u);
        }
      }
      __syncthreads();
      // matmul2: G = U @ Wp1^T (cols = d)
#pragma unroll
      for (int ks = 0; ks < 8; ++ks)
        af[ks] = *(const bf8*)&UL[l15 * 264 + ks * 32 + q * 8];
#pragma unroll
      for (int t = 0; t < 4; ++t) {
        acc[t] = fzero;
#pragma unroll
        for (int ks = 0; ks < 8; ++ks)
          acc[t] = __builtin_amdgcn_mfma_f32_16x16x32_bf16(af[ks], B2f[t][ks],
                                                           acc[t], 0, 0, 0);
      }
      // row reductions: gv = sum_c G*vs, vv = sum_c vs*vs
      float pg[4] = {0, 0, 0, 0}, pv[4] = {0, 0, 0, 0};
#pragma unroll
      for (int t = 0; t < 4; ++t)
#pragma unroll
        for (int rg = 0; rg < 4; ++rg) {
          const float vs = fmaf(cva, ap[t][rg], v[t][rg]);
          pg[rg] = fmaf(acc[t][rg], vs, pg[rg]);
          pv[rg] = fmaf(vs, vs, pv[rg]);
        }
#pragma unroll
      for (int sh = 1; sh < 16; sh <<= 1)
#pragma unroll
        for (int rg = 0; rg < 4; ++rg) {
          pg[rg] += __shfl_xor(pg[rg], sh);
          pv[rg] += __shfl_xor(pv[rg], sh);
        }
      if (l15 == 0)
#pragma unroll
        for (int rg = 0; rg < 4; ++rg) {
          gvp[w][rb + rg] = pg[rg];
          vvp[w][rb + rg] = pv[rg];
        }
      __syncthreads();
      float gv[4], vv[4];
#pragma unroll
      for (int rg = 0; rg < 4; ++rg) {
        gv[rg] = gvp[0][rb + rg] + gvp[1][rb + rg] + gvp[2][rb + rg] +
                 gvp[3][rb + rg];
        vv[rg] = vvp[0][rb + rg] + vvp[1][rb + rg] + vvp[2][rb + rg] +
                 vvp[3][rb + rg];
      }
      // accel + RK4 accumulation
#pragma unroll
      for (int t = 0; t < 4; ++t)
#pragma unroll
        for (int rg = 0; rg < 4; ++rg) {
          const float vs = fmaf(cva, ap[t][rg], v[t][rg]);
          const float a = -gv[rg] * vs + 0.5f * vv[rg] * acc[t][rg];
          ap[t][rg] = a;
          if (st == 0) {
            xacc[t][rg] = a;
            vacc[t][rg] = a;
          } else if (st < 3) {
            xacc[t][rg] += a;
            vacc[t][rg] += 2.0f * a;
          } else {
            vacc[t][rg] += a;
          }
        }
      if (st == 3) {  // step update + closest-approach
        float pd[4] = {0, 0, 0, 0};
#pragma unroll
        for (int t = 0; t < 4; ++t) {
          const int c = w * 64 + t * 16 + l15;
#pragma unroll
          for (int rg = 0; rg < 4; ++rg) {
            const size_t off = (size_t)(r0 + rb + rg) * 256 + c;
            const float xn =
                x[t][rg] + hs * v[t][rg] + (hs * hs / 6.0f) * xacc[t][rg];
            const float vn = v[t][rg] + (hs / 6.0f) * vacc[t][rg];
            x[t][rg] = xn;
            v[t][rg] = vn;
            const float d = xn - ZEg[off];
            pd[rg] = fmaf(d, d, pd[rg]);
          }
        }
#pragma unroll
        for (int sh = 1; sh < 16; sh <<= 1)
#pragma unroll
          for (int rg = 0; rg < 4; ++rg) pd[rg] += __shfl_xor(pd[rg], sh);
        if (l15 == 0)
#pragma unroll
          for (int rg = 0; rg < 4; ++rg) dp[w][rb + rg] = pd[rg];
        __syncthreads();
        if (tid < 16)
          mdL[tid] =
              fminf(mdL[tid], dp[0][tid] + dp[1][tid] + dp[2][tid] + dp[3][tid]);
      }
      __syncthreads();
    }
  }
  if (tid == 0) {
    float s = 0.0f;
#pragma unroll
    for (int i = 0; i < 16; ++i) s += mdL[i];
    atomicAdd(out, s * (1.0f / 4096.0f));
  }
}

}  // namespace

extern "C" void kernel_launch(void* const* d_in, const int* in_sizes, int n_in,
                              void* d_out, int out_size, void* d_ws,
                              size_t ws_size, hipStream_t stream) {
  (void)in_sizes; (void)n_in; (void)out_size; (void)ws_size;
  const float* x_start = (const float*)d_in[0];
  const float* x_end = (const float*)d_in[1];
  const float* noise = (const float*)d_in[2];
  const float* W1 = (const float*)d_in[3];
  const float* b1 = (const float*)d_in[4];
  const float* W2 = (const float*)d_in[5];
  const float* b2 = (const float*)d_in[6];
  const float* Ww1 = (const float*)d_in[7];
  const float* bw1 = (const float*)d_in[8];
  const float* Ww2 = (const float*)d_in[9];
  const float* bw2 = (const float*)d_in[10];
  const float* Wp1 = (const float*)d_in[11];
  const float* bp1 = (const float*)d_in[12];
  const float* wp2 = (const float*)d_in[13];
  float* out = (float*)d_out;

  // workspace layout (floats first, then bf16) — ~47 MB total
  float* Xf = (float*)d_ws;                    // z_s           4096*256 f32
  float* ZEf = Xf + (size_t)4096 * 256;        // z_e
  float* Vf = ZEf + (size_t)4096 * 256;        // W_start
  short* XSb = (short*)(Vf + (size_t)4096 * 256);  // x bf16   4096*2048
  short* H1b = XSb + (size_t)4096 * 2048;      // hidden bf16  4096*1024
  short* W1T = H1b + (size_t)4096 * 1024;      // W1^T bf16    1024*2048
  short* W2T = W1T + (size_t)1024 * 2048;      // W2^T bf16    256*1024
  short* Ww1T = W2T + (size_t)256 * 1024;      // 256*256
  short* Ww2T = Ww1T + 65536;
  short* WpT = Ww2T + 65536;                   // Wp1^T bf16
  short* Wp1b = WpT + 65536;                   // Wp1 bf16 row-major
  short* Xb = Wp1b + 65536;                    // z_s bf16     4096*256
  short* HWb = Xb + (size_t)4096 * 256;        // wind hidden bf16

  const dim3 blk(256);

  // weight converts/transposes
  cvt_t<<<dim3(32, 64), blk, 0, stream>>>(W1, W1T, 2048, 1024);
  cvt_t<<<dim3(8, 32), blk, 0, stream>>>(W2, W2T, 1024, 256);
  cvt_t<<<dim3(8, 8), blk, 0, stream>>>(Ww1, Ww1T, 256, 256);
  cvt_t<<<dim3(8, 8), blk, 0, stream>>>(Ww2, Ww2T, 256, 256);
  cvt_t<<<dim3(8, 8), blk, 0, stream>>>(Wp1, WpT, 256, 256);
  cvt_r<<<64, blk, 0, stream>>>(Wp1, Wp1b, 65536);

  // z_s = encode(x_start)  (dual-store: f32 for state, bf16 for wind MLP)
  cvt_r<<<4096, blk, 0, stream>>>(x_start, XSb, (long)4096 * 2048);
  gemm_bf16<128, 128, EPI_TANH><<<dim3(8, 32), blk, 0, stream>>>(
      XSb, W1T, b1, nullptr, H1b, 4096, 1024, 2048);
  gemm_bf16<128, 128, EPI_DUAL><<<dim3(2, 32), blk, 0, stream>>>(
      H1b, W2T, b2, Xf, Xb, 4096, 256, 1024);
  // z_e = encode(x_end)
  cvt_r<<<4096, blk, 0, stream>>>(x_end, XSb, (long)4096 * 2048);
  gemm_bf16<128, 128, EPI_TANH><<<dim3(8, 32), blk, 0, stream>>>(
      XSb, W1T, b1, nullptr, H1b, 4096, 1024, 2048);
  gemm_bf16<128, 128, EPI_F32><<<dim3(2, 32), blk, 0, stream>>>(
      H1b, W2T, b2, ZEf, nullptr, 4096, 256, 1024);
  // W_start = wind(z_s)
  gemm_bf16<128, 128, EPI_TANH><<<dim3(2, 32), blk, 0, stream>>>(
      Xb, Ww1T, bw1, nullptr, HWb, 4096, 256, 256);
  gemm_bf16<128, 128, EPI_F32><<<dim3(2, 32), blk, 0, stream>>>(
      HWb, Ww2T, bw2, Vf, nullptr, 4096, 256, 256);
  init_fb<<<1024, blk, 0, stream>>>(Vf, noise);

  hipMemsetAsync(d_out, 0, sizeof(float), stream);
  trace_fused<<<256, blk, 0, stream>>>(Xf, Vf, ZEf, WpT, Wp1b, bp1, wp2, out);
}

// Round 3
// 422.407 us; speedup vs baseline: 8.6546x; 1.1798x over previous
//
// Round 3: trace_fused at 2 waves/SIMD (512-thr blocks, 2 col-tiles/wave,
// fragment-ordered LDS); encoder GEMMs on m97-style global_load_lds staging.

#include <hip/hip_runtime.h>
#include <math.h>

typedef short bf8 __attribute__((ext_vector_type(8)));   // 8 bf16 = 4 VGPR
typedef float f32x4 __attribute__((ext_vector_type(4))); // MFMA acc

namespace {

constexpr float H_STEP = 1.0f / 15.0f;

__device__ inline short f2bf(float f) {  // RNE f32 -> bf16
  unsigned u = __float_as_uint(f);
  u += 0x7fffu + ((u >> 16) & 1u);
  return (short)(u >> 16);
}

__device__ inline float fast_tanh(float x) {
  const float ax = fabsf(x);
  const float e = __expf(-2.0f * ax);
  const float t = (1.0f - e) * __builtin_amdgcn_rcpf(1.0f + e);
  return copysignf(t, x);
}

__device__ inline float wave_sum(float v) {
#pragma unroll
  for (int sh = 32; sh > 0; sh >>= 1) v += __shfl_xor(v, sh);
  return v;
}

// async global->LDS, 16B per lane. LDS dest = wave-uniform base + lane*16.
__device__ inline void async16(const void* g, void* l) {
  __builtin_amdgcn_global_load_lds((__attribute__((address_space(1))) void*)g,
                                   (__attribute__((address_space(3))) void*)l,
                                   16, 0, 0);
}

// ---------------- converts ----------------

__global__ __launch_bounds__(256) void cvt_r(const float* __restrict__ src,
                                             short* __restrict__ dst, long n) {
  long i = ((long)blockIdx.x * 256 + threadIdx.x) * 4;
  const long stride = (long)gridDim.x * 1024;
  for (; i < n; i += stride) {
    const float4 f = *(const float4*)(src + i);
    ushort4 o;
    o.x = (unsigned short)f2bf(f.x);
    o.y = (unsigned short)f2bf(f.y);
    o.z = (unsigned short)f2bf(f.z);
    o.w = (unsigned short)f2bf(f.w);
    *(ushort4*)(dst + i) = o;
  }
}

// src [K][N] f32 -> dst [N][K] bf16 (transpose + convert)
__global__ __launch_bounds__(256) void cvt_t(const float* __restrict__ src,
                                             short* __restrict__ dst, int K,
                                             int N) {
  __shared__ float tile[32][33];
  const int k0 = blockIdx.y * 32, n0 = blockIdx.x * 32;
  const int tr = threadIdx.x >> 5, tc = threadIdx.x & 31;
#pragma unroll
  for (int i = 0; i < 32; i += 8)
    tile[tr + i][tc] = src[(size_t)(k0 + tr + i) * N + n0 + tc];
  __syncthreads();
#pragma unroll
  for (int i = 0; i < 32; i += 8)
    dst[(size_t)(n0 + tr + i) * K + k0 + tc] = f2bf(tile[tc][tr + i]);
}

// ---------------- bf16 TN GEMMs, global_load_lds staging ----------------

enum { EPI_TANH = 0, EPI_F32 = 1, EPI_DUAL = 2 };

template <int EPI>
__global__ __launch_bounds__(256) void gemm128(
    const short* __restrict__ A, const short* __restrict__ Bt,
    const float* __restrict__ bias, float* __restrict__ Cf,
    short* __restrict__ Cb, int M, int N, int K, int Mb) {
  __shared__ __align__(16) short As[128 * 32];
  __shared__ __align__(16) short Bs[128 * 32];
  const int tid = threadIdx.x;
  const int w = tid >> 6, lane = tid & 63, q = lane >> 4, l15 = lane & 15;
  const int wm = (w >> 1) * 64, wn = (w & 1) * 64;
  const int m0 = blockIdx.y * 128, n0 = blockIdx.x * 128;
  const f32x4 fzero = {0.0f, 0.0f, 0.0f, 0.0f};
  f32x4 acc[4][4];
#pragma unroll
  for (int mt = 0; mt < 4; ++mt)
#pragma unroll
    for (int nt = 0; nt < 4; ++nt) acc[mt][nt] = fzero;

  for (int k0 = 0; k0 < K; k0 += 32) {
#pragma unroll
    for (int j = 0; j < 2; ++j) {
      const int c = w * 128 + j * 64 + lane;  // chunk: row=c>>2, kq=c&3
      async16(A + (size_t)(m0 + (c >> 2)) * K + k0 + (c & 3) * 8,
              &As[(w * 128 + j * 64) * 8]);
      async16(Bt + (size_t)(n0 + (c >> 2)) * K + k0 + (c & 3) * 8,
              &Bs[(w * 128 + j * 64) * 8]);
    }
    __syncthreads();  // drains vmcnt
    bf8 af[4], bfr[4];
#pragma unroll
    for (int mt = 0; mt < 4; ++mt)
      af[mt] = *(const bf8*)&As[(wm + mt * 16 + l15) * 32 + q * 8];
#pragma unroll
    for (int nt = 0; nt < 4; ++nt)
      bfr[nt] = *(const bf8*)&Bs[(wn + nt * 16 + l15) * 32 + q * 8];
#pragma unroll
    for (int mt = 0; mt < 4; ++mt)
#pragma unroll
      for (int nt = 0; nt < 4; ++nt)
        acc[mt][nt] = __builtin_amdgcn_mfma_f32_16x16x32_bf16(
            af[mt], bfr[nt], acc[mt][nt], 0, 0, 0);
    __syncthreads();
  }
#pragma unroll
  for (int mt = 0; mt < 4; ++mt)
#pragma unroll
    for (int nt = 0; nt < 4; ++nt) {
      const int col = n0 + wn + nt * 16 + l15;
      const float bcol = bias[col];
#pragma unroll
      for (int rg = 0; rg < 4; ++rg) {
        const int row = m0 + wm + mt * 16 + q * 4 + rg;
        const float val = acc[mt][nt][rg] + bcol;
        if constexpr (EPI == EPI_TANH) {
          Cb[(size_t)row * N + col] = f2bf(fast_tanh(val));
        } else if constexpr (EPI == EPI_F32) {
          Cf[(size_t)row * N + col] = val;
        } else {
          Cf[(size_t)row * N + col] = val;
          if (row < Mb) Cb[(size_t)row * N + col] = f2bf(val);
        }
      }
    }
}

template <int EPI>
__global__ __launch_bounds__(256) void gemm64(
    const short* __restrict__ A, const short* __restrict__ Bt,
    const float* __restrict__ bias, float* __restrict__ Cf,
    short* __restrict__ Cb, int M, int N, int K, int Mb) {
  __shared__ __align__(16) short As[64 * 32];
  __shared__ __align__(16) short Bs[64 * 32];
  const int tid = threadIdx.x;
  const int w = tid >> 6, lane = tid & 63, q = lane >> 4, l15 = lane & 15;
  const int wm = (w >> 1) * 32, wn = (w & 1) * 32;
  const int m0 = blockIdx.y * 64, n0 = blockIdx.x * 64;
  const f32x4 fzero = {0.0f, 0.0f, 0.0f, 0.0f};
  f32x4 acc[2][2];
#pragma unroll
  for (int mt = 0; mt < 2; ++mt)
#pragma unroll
    for (int nt = 0; nt < 2; ++nt) acc[mt][nt] = fzero;

  for (int k0 = 0; k0 < K; k0 += 32) {
    const int c = w * 64 + lane;
    async16(A + (size_t)(m0 + (c >> 2)) * K + k0 + (c & 3) * 8,
            &As[(w * 64) * 8]);
    async16(Bt + (size_t)(n0 + (c >> 2)) * K + k0 + (c & 3) * 8,
            &Bs[(w * 64) * 8]);
    __syncthreads();
    bf8 af[2], bfr[2];
#pragma unroll
    for (int mt = 0; mt < 2; ++mt)
      af[mt] = *(const bf8*)&As[(wm + mt * 16 + l15) * 32 + q * 8];
#pragma unroll
    for (int nt = 0; nt < 2; ++nt)
      bfr[nt] = *(const bf8*)&Bs[(wn + nt * 16 + l15) * 32 + q * 8];
#pragma unroll
    for (int mt = 0; mt < 2; ++mt)
#pragma unroll
      for (int nt = 0; nt < 2; ++nt)
        acc[mt][nt] = __builtin_amdgcn_mfma_f32_16x16x32_bf16(
            af[mt], bfr[nt], acc[mt][nt], 0, 0, 0);
    __syncthreads();
  }
#pragma unroll
  for (int mt = 0; mt < 2; ++mt)
#pragma unroll
    for (int nt = 0; nt < 2; ++nt) {
      const int col = n0 + wn + nt * 16 + l15;
      const float bcol = bias[col];
#pragma unroll
      for (int rg = 0; rg < 4; ++rg) {
        const int row = m0 + wm + mt * 16 + q * 4 + rg;
        const float val = acc[mt][nt][rg] + bcol;
        if constexpr (EPI == EPI_TANH) {
          Cb[(size_t)row * N + col] = f2bf(fast_tanh(val));
        } else if constexpr (EPI == EPI_F32) {
          Cf[(size_t)row * N + col] = val;
        } else {
          Cf[(size_t)row * N + col] = val;
          if (row < Mb) Cb[(size_t)row * N + col] = f2bf(val);
        }
      }
    }
}

// ---------------- W_start fallback ----------------

__global__ __launch_bounds__(256) void init_fb(float* __restrict__ V,
                                               const float* __restrict__ nr) {
  const int row = blockIdx.x * 4 + (threadIdx.x >> 6);
  const int lane = threadIdx.x & 63;
  const size_t off = (size_t)row * 256 + (lane << 2);
  float4 wv = *(const float4*)(V + off);
  float s = wv.x * wv.x + wv.y * wv.y + wv.z * wv.z + wv.w * wv.w;
  s = wave_sum(s);
  const float wn = sqrtf(s + 1e-24f);
  if (wn < 1e-5f) {  // wave-uniform branch
    const float4 n4 = *(const float4*)(nr + off);
    float ns = n4.x * n4.x + n4.y * n4.y + n4.z * n4.z + n4.w * n4.w;
    ns = wave_sum(ns);
    const float nn = sqrtf(ns + 1e-24f);
    const float sc = 1e-4f / (nn + 1e-12f);
    wv.x += sc * n4.x; wv.y += sc * n4.y; wv.z += sc * n4.z; wv.w += sc * n4.w;
    *(float4*)(V + off) = wv;
  }
}

// ---------------- fused trace ----------------
// 256 blocks x 512 threads (8 waves, 2 waves/SIMD). Block owns 16 rows; wave
// w owns cols w*32 + t*16 + l15, t in {0,1}. B-frags of Wp1^T (matmul1) and
// Wp1 (matmul2) register-resident (128 VGPR). Activations round-trip LDS in
// fragment order: elem A[m][k] at short-index ((k>>3)*16+m)*8 + (k&7).

__global__ __launch_bounds__(512, 2) void trace_fused(
    const float* __restrict__ Xg, const float* __restrict__ Vg,
    const float* __restrict__ ZEg, const short* __restrict__ WT,
    const short* __restrict__ Wp1b, const float* __restrict__ bp1,
    const float* __restrict__ wp2, float* __restrict__ out) {
  constexpr float hs = H_STEP;
  __shared__ __align__(16) short XsL[4096];
  __shared__ __align__(16) short UL[4096];
  __shared__ float gvp[8][16], vvp[8][16];
  __shared__ float gvs[16], vvs[16];
  __shared__ float dpL[8][16];
  __shared__ float mdL[16];
  const int tid = threadIdx.x;
  const int w = tid >> 6, lane = tid & 63, q = lane >> 4, l15 = lane & 15;
  const int r0 = blockIdx.x * 16, rb = q * 4;

  bf8 B1f[2][8], B2f[2][8];
#pragma unroll
  for (int t = 0; t < 2; ++t) {
    const int n = w * 32 + t * 16 + l15;
#pragma unroll
    for (int ks = 0; ks < 8; ++ks) {
      B1f[t][ks] = *(const bf8*)(WT + n * 256 + ks * 32 + q * 8);
      B2f[t][ks] = *(const bf8*)(Wp1b + n * 256 + ks * 32 + q * 8);
    }
  }
  float x[2][4], v[2][4], ap[2][4], xacc[2][4], vacc[2][4];
  float bp1c[2], wp2c[2];
  int wb[2];  // LDS short-index base per t; addr(row r) = wb[t] + r*8
#pragma unroll
  for (int t = 0; t < 2; ++t) {
    const int c = w * 32 + t * 16 + l15;
    wb[t] = (c >> 3) * 128 + (c & 7);
    bp1c[t] = bp1[c];
    wp2c[t] = wp2[c];
#pragma unroll
    for (int rg = 0; rg < 4; ++rg) {
      const size_t off = (size_t)(r0 + rb + rg) * 256 + c;
      x[t][rg] = Xg[off];
      v[t][rg] = Vg[off];
      ap[t][rg] = 0.0f;
      xacc[t][rg] = 0.0f;
      vacc[t][rg] = 0.0f;
    }
  }
  if (tid < 16) mdL[tid] = 3.4e38f;
  const int rd0 = (q * 16 + l15) * 8;
  const f32x4 fzero = {0.0f, 0.0f, 0.0f, 0.0f};
  const float cxv_t[4] = {0.0f, 0.5f * hs, 0.5f * hs, hs};
  const float cxa_t[4] = {0.0f, 0.0f, 0.25f * hs * hs, 0.5f * hs * hs};
  const float cva_t[4] = {0.0f, 0.5f * hs, 0.5f * hs, hs};

#pragma unroll 1
  for (int step = 0; step < 15; ++step) {
#pragma unroll
    for (int st = 0; st < 4; ++st) {
      const float cxv = cxv_t[st], cxa = cxa_t[st], cva = cva_t[st];
      // stage position -> LDS (fragment order)
#pragma unroll
      for (int t = 0; t < 2; ++t)
#pragma unroll
        for (int rg = 0; rg < 4; ++rg) {
          const float xs = x[t][rg] + cxv * v[t][rg] + cxa * ap[t][rg];
          XsL[wb[t] + (rb + rg) * 8] = f2bf(xs);
        }
      __syncthreads();
      // matmul1: H = Xs @ Wp1
      bf8 af[8];
#pragma unroll
      for (int ks = 0; ks < 8; ++ks)
        af[ks] = *(const bf8*)&XsL[rd0 + ks * 512];
      f32x4 acc[2];
#pragma unroll
      for (int t = 0; t < 2; ++t) {
        acc[t] = fzero;
#pragma unroll
        for (int ks = 0; ks < 8; ++ks)
          acc[t] = __builtin_amdgcn_mfma_f32_16x16x32_bf16(af[ks], B1f[t][ks],
                                                           acc[t], 0, 0, 0);
      }
      // epilogue1: U = (1 - tanh^2) * wp2 -> LDS
#pragma unroll
      for (int t = 0; t < 2; ++t)
#pragma unroll
        for (int rg = 0; rg < 4; ++rg) {
          const float s = acc[t][rg] + bp1c[t];
          const float th = fast_tanh(s);
          UL[wb[t] + (rb + rg) * 8] = f2bf((1.0f - th * th) * wp2c[t]);
        }
      __syncthreads();
      // matmul2: G = U @ Wp1^T
#pragma unroll
      for (int ks = 0; ks < 8; ++ks)
        af[ks] = *(const bf8*)&UL[rd0 + ks * 512];
#pragma unroll
      for (int t = 0; t < 2; ++t) {
        acc[t] = fzero;
#pragma unroll
        for (int ks = 0; ks < 8; ++ks)
          acc[t] = __builtin_amdgcn_mfma_f32_16x16x32_bf16(af[ks], B2f[t][ks],
                                                           acc[t], 0, 0, 0);
      }
      // row reductions: gv = sum_c G*vs, vv = sum_c vs*vs
      float pg[4] = {0, 0, 0, 0}, pv[4] = {0, 0, 0, 0};
#pragma unroll
      for (int t = 0; t < 2; ++t)
#pragma unroll
        for (int rg = 0; rg < 4; ++rg) {
          const float vs = fmaf(cva, ap[t][rg], v[t][rg]);
          pg[rg] = fmaf(acc[t][rg], vs, pg[rg]);
          pv[rg] = fmaf(vs, vs, pv[rg]);
        }
#pragma unroll
      for (int sh = 1; sh < 16; sh <<= 1)
#pragma unroll
        for (int rg = 0; rg < 4; ++rg) {
          pg[rg] += __shfl_xor(pg[rg], sh);
          pv[rg] += __shfl_xor(pv[rg], sh);
        }
      if (l15 == 0)
#pragma unroll
        for (int rg = 0; rg < 4; ++rg) {
          gvp[w][rb + rg] = pg[rg];
          vvp[w][rb + rg] = pv[rg];
        }
      __syncthreads();
      if (tid < 32) {
        const int r = tid & 15;
        float s = 0.0f;
        if (tid < 16) {
#pragma unroll
          for (int ww = 0; ww < 8; ++ww) s += gvp[ww][r];
          gvs[r] = s;
        } else {
#pragma unroll
          for (int ww = 0; ww < 8; ++ww) s += vvp[ww][r];
          vvs[r] = s;
        }
      }
      __syncthreads();
      float gv[4], vv[4];
#pragma unroll
      for (int rg = 0; rg < 4; ++rg) {
        gv[rg] = gvs[rb + rg];
        vv[rg] = vvs[rb + rg];
      }
      // accel + RK4 accumulation
#pragma unroll
      for (int t = 0; t < 2; ++t)
#pragma unroll
        for (int rg = 0; rg < 4; ++rg) {
          const float vs = fmaf(cva, ap[t][rg], v[t][rg]);
          const float a = -gv[rg] * vs + 0.5f * vv[rg] * acc[t][rg];
          ap[t][rg] = a;
          if (st == 0) {
            xacc[t][rg] = a;
            vacc[t][rg] = a;
          } else if (st < 3) {
            xacc[t][rg] += a;
            vacc[t][rg] += 2.0f * a;
          } else {
            vacc[t][rg] += a;
          }
        }
      if (st == 3) {  // step update + closest approach
        float pd[4] = {0, 0, 0, 0};
#pragma unroll
        for (int t = 0; t < 2; ++t) {
          const int c = w * 32 + t * 16 + l15;
#pragma unroll
          for (int rg = 0; rg < 4; ++rg) {
            const float xn =
                x[t][rg] + hs * v[t][rg] + (hs * hs / 6.0f) * xacc[t][rg];
            const float vn = v[t][rg] + (hs / 6.0f) * vacc[t][rg];
            x[t][rg] = xn;
            v[t][rg] = vn;
            const float d = xn - ZEg[(size_t)(r0 + rb + rg) * 256 + c];
            pd[rg] = fmaf(d, d, pd[rg]);
          }
        }
#pragma unroll
        for (int sh = 1; sh < 16; sh <<= 1)
#pragma unroll
          for (int rg = 0; rg < 4; ++rg) pd[rg] += __shfl_xor(pd[rg], sh);
        if (l15 == 0)
#pragma unroll
          for (int rg = 0; rg < 4; ++rg) dpL[w][rb + rg] = pd[rg];
        __syncthreads();
        if (tid < 16) {
          float s = 0.0f;
#pragma unroll
          for (int ww = 0; ww < 8; ++ww) s += dpL[ww][tid];
          mdL[tid] = fminf(mdL[tid], s);
        }
      }
    }
  }
  if (tid == 0) {
    float s = 0.0f;
#pragma unroll
    for (int i = 0; i < 16; ++i) s += mdL[i];
    atomicAdd(out, s * (1.0f / 4096.0f));
  }
}

}  // namespace

extern "C" void kernel_launch(void* const* d_in, const int* in_sizes, int n_in,
                              void* d_out, int out_size, void* d_ws,
                              size_t ws_size, hipStream_t stream) {
  (void)in_sizes; (void)n_in; (void)out_size; (void)ws_size;
  const float* x_start = (const float*)d_in[0];
  const float* x_end = (const float*)d_in[1];
  const float* noise = (const float*)d_in[2];
  const float* W1 = (const float*)d_in[3];
  const float* b1 = (const float*)d_in[4];
  const float* W2 = (const float*)d_in[5];
  const float* b2 = (const float*)d_in[6];
  const float* Ww1 = (const float*)d_in[7];
  const float* bw1 = (const float*)d_in[8];
  const float* Ww2 = (const float*)d_in[9];
  const float* bw2 = (const float*)d_in[10];
  const float* Wp1 = (const float*)d_in[11];
  const float* bp1 = (const float*)d_in[12];
  const float* wp2 = (const float*)d_in[13];
  float* out = (float*)d_out;

  // workspace layout (~45 MB)
  float* Xf = (float*)d_ws;                        // z_s      4096*256 f32
  float* ZEf = Xf + (size_t)4096 * 256;            // z_e
  float* Vf = ZEf + (size_t)4096 * 256;            // W_start
  short* Xb = (short*)(Vf + (size_t)4096 * 256);   // z_s bf16 4096*256
  short* HWb = Xb + (size_t)4096 * 256;            // wind hidden bf16
  short* XSb = HWb + (size_t)4096 * 256;           // x bf16   4096*2048
  short* H1b = XSb + (size_t)4096 * 2048;          // enc hidden bf16 4096*1024
  short* W1T = H1b + (size_t)4096 * 1024;          // 1024*2048
  short* W2T = W1T + (size_t)1024 * 2048;          // 256*1024
  short* Ww1T = W2T + (size_t)256 * 1024;
  short* Ww2T = Ww1T + 65536;
  short* WpT = Ww2T + 65536;                       // Wp1^T
  short* Wp1b = WpT + 65536;                       // Wp1 row-major

  const dim3 blk(256);

  cvt_t<<<dim3(32, 64), blk, 0, stream>>>(W1, W1T, 2048, 1024);
  cvt_t<<<dim3(8, 32), blk, 0, stream>>>(W2, W2T, 1024, 256);
  cvt_t<<<dim3(8, 8), blk, 0, stream>>>(Ww1, Ww1T, 256, 256);
  cvt_t<<<dim3(8, 8), blk, 0, stream>>>(Ww2, Ww2T, 256, 256);
  cvt_t<<<dim3(8, 8), blk, 0, stream>>>(Wp1, WpT, 256, 256);
  cvt_r<<<64, blk, 0, stream>>>(Wp1, Wp1b, 65536);

  // z_s = encode(x_start): dual-store f32 (state) + bf16 (wind input)
  cvt_r<<<2048, blk, 0, stream>>>(x_start, XSb, (long)4096 * 2048);
  gemm128<EPI_TANH><<<dim3(8, 32), blk, 0, stream>>>(
      XSb, W1T, b1, nullptr, H1b, 4096, 1024, 2048, 0);
  gemm64<EPI_DUAL><<<dim3(4, 64), blk, 0, stream>>>(
      H1b, W2T, b2, Xf, Xb, 4096, 256, 1024, 4096);
  // z_e = encode(x_end)
  cvt_r<<<2048, blk, 0, stream>>>(x_end, XSb, (long)4096 * 2048);
  gemm128<EPI_TANH><<<dim3(8, 32), blk, 0, stream>>>(
      XSb, W1T, b1, nullptr, H1b, 4096, 1024, 2048, 0);
  gemm64<EPI_F32><<<dim3(4, 64), blk, 0, stream>>>(
      H1b, W2T, b2, ZEf, nullptr, 4096, 256, 1024, 0);
  // W_start = wind(z_s)
  gemm64<EPI_TANH><<<dim3(4, 64), blk, 0, stream>>>(
      Xb, Ww1T, bw1, nullptr, HWb, 4096, 256, 256, 0);
  gemm64<EPI_F32><<<dim3(4, 64), blk, 0, stream>>>(
      HWb, Ww2T, bw2, Vf, nullptr, 4096, 256, 256, 0);
  init_fb<<<1024, blk, 0, stream>>>(Vf, noise);

  hipMemsetAsync(d_out, 0, sizeof(float), stream);
  trace_fused<<<256, dim3(512), 0, stream>>>(Xf, Vf, ZEf, WpT, Wp1b, bp1, wp2,
                                             out);
}

// Round 4
// 345.987 us; speedup vs baseline: 10.5662x; 1.2209x over previous
//
// Round 4: encoder consolidated (M=8192 fused z_s/z_e, 2 blocks/CU grids);
// trace: 3 barriers/stage, DPP row_ror reductions, LDS-atomic ping-pong
// row-sums with broadcast re-read, XOR-swizzled activation LDS layout.

#include <hip/hip_runtime.h>
#include <math.h>

typedef short bf8 __attribute__((ext_vector_type(8)));   // 8 bf16 = 4 VGPR
typedef float f32x4 __attribute__((ext_vector_type(4))); // MFMA acc

namespace {

constexpr float H_STEP = 1.0f / 15.0f;

__device__ inline short f2bf(float f) {  // RNE f32 -> bf16
  unsigned u = __float_as_uint(f);
  u += 0x7fffu + ((u >> 16) & 1u);
  return (short)(u >> 16);
}

__device__ inline float fast_tanh(float x) {
  const float ax = fabsf(x);
  const float e = __expf(-2.0f * ax);
  const float t = (1.0f - e) * __builtin_amdgcn_rcpf(1.0f + e);
  return copysignf(t, x);
}

__device__ inline float wave_sum(float v) {
#pragma unroll
  for (int sh = 32; sh > 0; sh >>= 1) v += __shfl_xor(v, sh);
  return v;
}

// sum over each 16-lane row via DPP row_ror 1/2/4/8 (VALU-rate butterfly)
template <int CTRL>
__device__ inline float dppadd(float v) {
  return v + __int_as_float(__builtin_amdgcn_update_dpp(
                 0, __float_as_int(v), CTRL, 0xF, 0xF, true));
}
__device__ inline float red16(float v) {
  v = dppadd<0x121>(v);  // row_ror:1
  v = dppadd<0x122>(v);  // row_ror:2
  v = dppadd<0x124>(v);  // row_ror:4
  v = dppadd<0x128>(v);  // row_ror:8
  return v;
}

// async global->LDS, 16B per lane. LDS dest = wave-uniform base + lane*16.
__device__ inline void async16(const void* g, void* l) {
  __builtin_amdgcn_global_load_lds((__attribute__((address_space(1))) void*)g,
                                   (__attribute__((address_space(3))) void*)l,
                                   16, 0, 0);
}

// ---------------- converts ----------------

// both encoder inputs -> one bf16 buffer [8192][2048]
__global__ __launch_bounds__(256) void cvt2(const float* __restrict__ a,
                                            const float* __restrict__ b,
                                            short* __restrict__ dst, long n) {
  const long half = n >> 1;
  long i = ((long)blockIdx.x * 256 + threadIdx.x) * 4;
  const long stride = (long)gridDim.x * 1024;
  for (; i < n; i += stride) {
    const float* s = (i < half) ? (a + i) : (b + (i - half));
    const float4 f = *(const float4*)s;
    ushort4 o;
    o.x = (unsigned short)f2bf(f.x);
    o.y = (unsigned short)f2bf(f.y);
    o.z = (unsigned short)f2bf(f.z);
    o.w = (unsigned short)f2bf(f.w);
    *(ushort4*)(dst + i) = o;
  }
}

// src [K][N] f32 -> dst [N][K] bf16 (transpose + convert)
__global__ __launch_bounds__(256) void cvt_t(const float* __restrict__ src,
                                             short* __restrict__ dst, int K,
                                             int N) {
  __shared__ float tile[32][33];
  const int k0 = blockIdx.y * 32, n0 = blockIdx.x * 32;
  const int tr = threadIdx.x >> 5, tc = threadIdx.x & 31;
#pragma unroll
  for (int i = 0; i < 32; i += 8)
    tile[tr + i][tc] = src[(size_t)(k0 + tr + i) * N + n0 + tc];
  __syncthreads();
#pragma unroll
  for (int i = 0; i < 32; i += 8)
    dst[(size_t)(n0 + tr + i) * K + k0 + tc] = f2bf(tile[tc][tr + i]);
}

// batched 256x256 weight converts: z=0..2 transpose Ww1/Ww2/Wp1, z=3 copy Wp1
__global__ __launch_bounds__(256) void cvt4(const float* __restrict__ Ww1,
                                            const float* __restrict__ Ww2,
                                            const float* __restrict__ Wp1,
                                            short* __restrict__ d0,
                                            short* __restrict__ d1,
                                            short* __restrict__ d2,
                                            short* __restrict__ d3) {
  __shared__ float tile[32][33];
  const int z = blockIdx.z;
  const int k0 = blockIdx.y * 32, n0 = blockIdx.x * 32;
  const int tr = threadIdx.x >> 5, tc = threadIdx.x & 31;
  if (z == 3) {
#pragma unroll
    for (int i = 0; i < 32; i += 8) {
      const size_t o = (size_t)(k0 + tr + i) * 256 + n0 + tc;
      d3[o] = f2bf(Wp1[o]);
    }
    return;
  }
  const float* src = (z == 0) ? Ww1 : (z == 1) ? Ww2 : Wp1;
  short* dst = (z == 0) ? d0 : (z == 1) ? d1 : d2;
#pragma unroll
  for (int i = 0; i < 32; i += 8)
    tile[tr + i][tc] = src[(size_t)(k0 + tr + i) * 256 + n0 + tc];
  __syncthreads();
#pragma unroll
  for (int i = 0; i < 32; i += 8)
    dst[(size_t)(n0 + tr + i) * 256 + k0 + tc] = f2bf(tile[tc][tr + i]);
}

// ---------------- bf16 TN GEMMs, global_load_lds staging ----------------

enum { EPI_TANH = 0, EPI_F32 = 1, EPI_ENC2 = 2 };

template <int EPI>
__global__ __launch_bounds__(256) void gemm128(
    const short* __restrict__ A, const short* __restrict__ Bt,
    const float* __restrict__ bias, float* __restrict__ Cf,
    short* __restrict__ Cb, int M, int N, int K) {
  __shared__ __align__(16) short As[128 * 32];
  __shared__ __align__(16) short Bs[128 * 32];
  const int tid = threadIdx.x;
  const int w = tid >> 6, lane = tid & 63, q = lane >> 4, l15 = lane & 15;
  const int wm = (w >> 1) * 64, wn = (w & 1) * 64;
  const int m0 = blockIdx.y * 128, n0 = blockIdx.x * 128;
  const f32x4 fzero = {0.0f, 0.0f, 0.0f, 0.0f};
  f32x4 acc[4][4];
#pragma unroll
  for (int mt = 0; mt < 4; ++mt)
#pragma unroll
    for (int nt = 0; nt < 4; ++nt) acc[mt][nt] = fzero;

  for (int k0 = 0; k0 < K; k0 += 32) {
#pragma unroll
    for (int j = 0; j < 2; ++j) {
      const int c = w * 128 + j * 64 + lane;
      async16(A + (size_t)(m0 + (c >> 2)) * K + k0 + (c & 3) * 8,
              &As[(w * 128 + j * 64) * 8]);
      async16(Bt + (size_t)(n0 + (c >> 2)) * K + k0 + (c & 3) * 8,
              &Bs[(w * 128 + j * 64) * 8]);
    }
    __syncthreads();
    bf8 af[4], bfr[4];
#pragma unroll
    for (int mt = 0; mt < 4; ++mt)
      af[mt] = *(const bf8*)&As[(wm + mt * 16 + l15) * 32 + q * 8];
#pragma unroll
    for (int nt = 0; nt < 4; ++nt)
      bfr[nt] = *(const bf8*)&Bs[(wn + nt * 16 + l15) * 32 + q * 8];
#pragma unroll
    for (int mt = 0; mt < 4; ++mt)
#pragma unroll
      for (int nt = 0; nt < 4; ++nt)
        acc[mt][nt] = __builtin_amdgcn_mfma_f32_16x16x32_bf16(
            af[mt], bfr[nt], acc[mt][nt], 0, 0, 0);
    __syncthreads();
  }
#pragma unroll
  for (int mt = 0; mt < 4; ++mt)
#pragma unroll
    for (int nt = 0; nt < 4; ++nt) {
      const int col = n0 + wn + nt * 16 + l15;
      const float bcol = bias[col];
#pragma unroll
      for (int rg = 0; rg < 4; ++rg) {
        const int row = m0 + wm + mt * 16 + q * 4 + rg;
        const float val = acc[mt][nt][rg] + bcol;
        if constexpr (EPI == EPI_TANH) {
          Cb[(size_t)row * N + col] = f2bf(fast_tanh(val));
        } else {
          Cf[(size_t)row * N + col] = val;
        }
      }
    }
}

template <int EPI>
__global__ __launch_bounds__(256) void gemm64(
    const short* __restrict__ A, const short* __restrict__ Bt,
    const float* __restrict__ bias, float* __restrict__ Cf,
    short* __restrict__ Cb, float* __restrict__ Cf2, int M, int N, int K) {
  __shared__ __align__(16) short As[64 * 32];
  __shared__ __align__(16) short Bs[64 * 32];
  const int tid = threadIdx.x;
  const int w = tid >> 6, lane = tid & 63, q = lane >> 4, l15 = lane & 15;
  const int wm = (w >> 1) * 32, wn = (w & 1) * 32;
  const int m0 = blockIdx.y * 64, n0 = blockIdx.x * 64;
  const f32x4 fzero = {0.0f, 0.0f, 0.0f, 0.0f};
  f32x4 acc[2][2];
#pragma unroll
  for (int mt = 0; mt < 2; ++mt)
#pragma unroll
    for (int nt = 0; nt < 2; ++nt) acc[mt][nt] = fzero;

  for (int k0 = 0; k0 < K; k0 += 32) {
    const int c = w * 64 + lane;
    async16(A + (size_t)(m0 + (c >> 2)) * K + k0 + (c & 3) * 8,
            &As[(w * 64) * 8]);
    async16(Bt + (size_t)(n0 + (c >> 2)) * K + k0 + (c & 3) * 8,
            &Bs[(w * 64) * 8]);
    __syncthreads();
    bf8 af[2], bfr[2];
#pragma unroll
    for (int mt = 0; mt < 2; ++mt)
      af[mt] = *(const bf8*)&As[(wm + mt * 16 + l15) * 32 + q * 8];
#pragma unroll
    for (int nt = 0; nt < 2; ++nt)
      bfr[nt] = *(const bf8*)&Bs[(wn + nt * 16 + l15) * 32 + q * 8];
#pragma unroll
    for (int mt = 0; mt < 2; ++mt)
#pragma unroll
      for (int nt = 0; nt < 2; ++nt)
        acc[mt][nt] = __builtin_amdgcn_mfma_f32_16x16x32_bf16(
            af[mt], bfr[nt], acc[mt][nt], 0, 0, 0);
    __syncthreads();
  }
#pragma unroll
  for (int mt = 0; mt < 2; ++mt)
#pragma unroll
    for (int nt = 0; nt < 2; ++nt) {
      const int col = n0 + wn + nt * 16 + l15;
      const float bcol = bias[col];
#pragma unroll
      for (int rg = 0; rg < 4; ++rg) {
        const int row = m0 + wm + mt * 16 + q * 4 + rg;
        const float val = acc[mt][nt][rg] + bcol;
        if constexpr (EPI == EPI_TANH) {
          Cb[(size_t)row * N + col] = f2bf(fast_tanh(val));
        } else if constexpr (EPI == EPI_F32) {
          Cf[(size_t)row * N + col] = val;
        } else {  // EPI_ENC2: rows<4096 -> z_s (f32+bf16); rows>=4096 -> z_e
          if (row < 4096) {
            Cf[(size_t)row * N + col] = val;
            Cb[(size_t)row * N + col] = f2bf(val);
          } else {
            Cf2[(size_t)(row - 4096) * N + col] = val;
          }
        }
      }
    }
}

// ---------------- W_start fallback ----------------

__global__ __launch_bounds__(256) void init_fb(float* __restrict__ V,
                                               const float* __restrict__ nr) {
  const int row = blockIdx.x * 4 + (threadIdx.x >> 6);
  const int lane = threadIdx.x & 63;
  const size_t off = (size_t)row * 256 + (lane << 2);
  float4 wv = *(const float4*)(V + off);
  float s = wv.x * wv.x + wv.y * wv.y + wv.z * wv.z + wv.w * wv.w;
  s = wave_sum(s);
  const float wn = sqrtf(s + 1e-24f);
  if (wn < 1e-5f) {  // wave-uniform branch
    const float4 n4 = *(const float4*)(nr + off);
    float ns = n4.x * n4.x + n4.y * n4.y + n4.z * n4.z + n4.w * n4.w;
    ns = wave_sum(ns);
    const float nn = sqrtf(ns + 1e-24f);
    const float sc = 1e-4f / (nn + 1e-12f);
    wv.x += sc * n4.x; wv.y += sc * n4.y; wv.z += sc * n4.z; wv.w += sc * n4.w;
    *(float4*)(V + off) = wv;
  }
}

// ---------------- fused trace ----------------
// 256 blocks x 512 threads (8 waves, 2/SIMD). Wave w owns cols w*32+t*16+l15.
// Activation LDS in XOR-swizzled chunks: elem (m,k) at chunk kc*16+(m^(kc&15))
// (kc=k>>3), 8 shorts each -> b128 reads stay lane*16B, u16 writes 2-way.
// Row-sums: DPP row_ror butterfly -> l15==0 LDS atomicAdd into ping-pong
// buffers (parity st&1; zeroed two stages ahead) -> broadcast float4 read.

__global__ __launch_bounds__(512, 2) void trace_fused(
    const float* __restrict__ Xg, const float* __restrict__ Vg,
    const float* __restrict__ ZEg, const short* __restrict__ WT,
    const short* __restrict__ Wp1b, const float* __restrict__ bp1,
    const float* __restrict__ wp2, float* __restrict__ out) {
  constexpr float hs = H_STEP;
  __shared__ __align__(16) short XsL[4096];
  __shared__ __align__(16) short UL[4096];
  __shared__ __align__(16) float gvb[2][16];
  __shared__ __align__(16) float vvb[2][16];
  __shared__ __align__(16) float db[2][16];
  const int tid = threadIdx.x;
  const int w = tid >> 6, lane = tid & 63, q = lane >> 4, l15 = lane & 15;
  const int r0 = blockIdx.x * 16, rb = q * 4;

  if (tid < 16) {
    gvb[0][tid] = 0.0f; gvb[1][tid] = 0.0f;
    vvb[0][tid] = 0.0f; vvb[1][tid] = 0.0f;
    db[0][tid] = 0.0f;  db[1][tid] = 0.0f;
  }

  bf8 B1f[2][8], B2f[2][8];
  int wadr[2][4], radr[8];
  float bp1c[2], wp2c[2];
  float x[2][4], v[2][4], ap[2][4], xacc[2][4], vacc[2][4], ze[2][4], md[4];
#pragma unroll
  for (int t = 0; t < 2; ++t) {
    const int c = w * 32 + t * 16 + l15;
    const int kc = c >> 3, cx = kc & 15, cl = c & 7;
#pragma unroll
    for (int ks = 0; ks < 8; ++ks) {
      B1f[t][ks] = *(const bf8*)(WT + c * 256 + ks * 32 + q * 8);    // Wp1^T
      B2f[t][ks] = *(const bf8*)(Wp1b + c * 256 + ks * 32 + q * 8);  // Wp1
    }
    bp1c[t] = bp1[c];
    wp2c[t] = wp2[c];
#pragma unroll
    for (int rg = 0; rg < 4; ++rg) {
      wadr[t][rg] = kc * 128 + ((rb + rg) ^ cx) * 8 + cl;
      const size_t off = (size_t)(r0 + rb + rg) * 256 + c;
      x[t][rg] = Xg[off];
      v[t][rg] = Vg[off];
      ze[t][rg] = ZEg[off];
      ap[t][rg] = 0.0f;
      xacc[t][rg] = 0.0f;
      vacc[t][rg] = 0.0f;
    }
  }
#pragma unroll
  for (int ks = 0; ks < 8; ++ks) {
    const int kq = ks * 4 + q;
    radr[ks] = (kq * 16 + (l15 ^ (kq & 15))) * 8;
  }
#pragma unroll
  for (int rg = 0; rg < 4; ++rg) md[rg] = 3.4e38f;
  const f32x4 fzero = {0.0f, 0.0f, 0.0f, 0.0f};
  const float cxv_t[4] = {0.0f, 0.5f * hs, 0.5f * hs, hs};
  const float cxa_t[4] = {0.0f, 0.0f, 0.25f * hs * hs, 0.5f * hs * hs};
  const float cva_t[4] = {0.0f, 0.5f * hs, 0.5f * hs, hs};

#pragma unroll 1
  for (int step = 0; step < 15; ++step) {
#pragma unroll
    for (int st = 0; st < 4; ++st) {
      const int p = st & 1;  // stage parity (step*4 is even)
      const float cxv = cxv_t[st], cxa = cxa_t[st], cva = cva_t[st];
      // 1. stage position -> LDS
#pragma unroll
      for (int t = 0; t < 2; ++t)
#pragma unroll
        for (int rg = 0; rg < 4; ++rg)
          XsL[wadr[t][rg]] =
              f2bf(x[t][rg] + cxv * v[t][rg] + cxa * ap[t][rg]);
      __syncthreads();
      // 2. matmul1: H = Xs @ Wp1 (two acc chains per t)
      bf8 af[8];
#pragma unroll
      for (int ks = 0; ks < 8; ++ks) af[ks] = *(const bf8*)&XsL[radr[ks]];
      f32x4 acc[2];
#pragma unroll
      for (int t = 0; t < 2; ++t) {
        f32x4 a0 = fzero, a1 = fzero;
#pragma unroll
        for (int ks = 0; ks < 8; ks += 2) {
          a0 = __builtin_amdgcn_mfma_f32_16x16x32_bf16(af[ks], B1f[t][ks], a0,
                                                       0, 0, 0);
          a1 = __builtin_amdgcn_mfma_f32_16x16x32_bf16(af[ks + 1],
                                                       B1f[t][ks + 1], a1, 0,
                                                       0, 0);
        }
        acc[t] = a0 + a1;
      }
      // epilogue1: U = (1 - tanh^2) * wp2 -> LDS; zero next stage's buffers
#pragma unroll
      for (int t = 0; t < 2; ++t)
#pragma unroll
        for (int rg = 0; rg < 4; ++rg) {
          const float th = fast_tanh(acc[t][rg] + bp1c[t]);
          UL[wadr[t][rg]] = f2bf((1.0f - th * th) * wp2c[t]);
        }
      if (tid < 16) {
        gvb[p ^ 1][tid] = 0.0f;
        vvb[p ^ 1][tid] = 0.0f;
      }
      __syncthreads();
      // 3. matmul2: G = U @ Wp1^T
#pragma unroll
      for (int ks = 0; ks < 8; ++ks) af[ks] = *(const bf8*)&UL[radr[ks]];
#pragma unroll
      for (int t = 0; t < 2; ++t) {
        f32x4 a0 = fzero, a1 = fzero;
#pragma unroll
        for (int ks = 0; ks < 8; ks += 2) {
          a0 = __builtin_amdgcn_mfma_f32_16x16x32_bf16(af[ks], B2f[t][ks], a0,
                                                       0, 0, 0);
          a1 = __builtin_amdgcn_mfma_f32_16x16x32_bf16(af[ks + 1],
                                                       B2f[t][ks + 1], a1, 0,
                                                       0, 0);
        }
        acc[t] = a0 + a1;
      }
      // row partials over this wave's 32 cols, DPP-reduce, LDS atomics
      float pg[4] = {0, 0, 0, 0}, pv[4] = {0, 0, 0, 0};
#pragma unroll
      for (int t = 0; t < 2; ++t)
#pragma unroll
        for (int rg = 0; rg < 4; ++rg) {
          const float vs = fmaf(cva, ap[t][rg], v[t][rg]);
          pg[rg] = fmaf(acc[t][rg], vs, pg[rg]);
          pv[rg] = fmaf(vs, vs, pv[rg]);
        }
#pragma unroll
      for (int rg = 0; rg < 4; ++rg) {
        pg[rg] = red16(pg[rg]);
        pv[rg] = red16(pv[rg]);
      }
      if (l15 == 0) {
#pragma unroll
        for (int rg = 0; rg < 4; ++rg) {
          atomicAdd(&gvb[p][rb + rg], pg[rg]);
          atomicAdd(&vvb[p][rb + rg], pv[rg]);
        }
      }
      __syncthreads();
      // 4. broadcast read + accel + RK4 accumulation
      const f32x4 gv4 = *(const f32x4*)&gvb[p][rb];
      const f32x4 vv4 = *(const f32x4*)&vvb[p][rb];
#pragma unroll
      for (int t = 0; t < 2; ++t)
#pragma unroll
        for (int rg = 0; rg < 4; ++rg) {
          const float vs = fmaf(cva, ap[t][rg], v[t][rg]);
          const float a = -gv4[rg] * vs + 0.5f * vv4[rg] * acc[t][rg];
          ap[t][rg] = a;
          if (st == 0) {
            xacc[t][rg] = a;
            vacc[t][rg] = a;
          } else if (st < 3) {
            xacc[t][rg] += a;
            vacc[t][rg] += 2.0f * a;
          } else {
            vacc[t][rg] += a;
          }
        }
      // 5. step update + closest approach
      if (st == 3) {
        const int sp = step & 1;
        float pd[4] = {0, 0, 0, 0};
#pragma unroll
        for (int t = 0; t < 2; ++t)
#pragma unroll
          for (int rg = 0; rg < 4; ++rg) {
            const float xn =
                x[t][rg] + hs * v[t][rg] + (hs * hs / 6.0f) * xacc[t][rg];
            const float vn = v[t][rg] + (hs / 6.0f) * vacc[t][rg];
            x[t][rg] = xn;
            v[t][rg] = vn;
            const float d = xn - ze[t][rg];
            pd[rg] = fmaf(d, d, pd[rg]);
          }
#pragma unroll
        for (int rg = 0; rg < 4; ++rg) pd[rg] = red16(pd[rg]);
        if (l15 == 0) {
#pragma unroll
          for (int rg = 0; rg < 4; ++rg) atomicAdd(&db[sp][rb + rg], pd[rg]);
        }
        if (tid < 16) db[sp ^ 1][tid] = 0.0f;
        __syncthreads();
        const f32x4 d4 = *(const f32x4*)&db[sp][rb];
#pragma unroll
        for (int rg = 0; rg < 4; ++rg) md[rg] = fminf(md[rg], d4[rg]);
      }
    }
  }
  if (w == 0 && l15 == 0)  // q=0..3 cover rows 0..15, md replicated elsewhere
    atomicAdd(out, (md[0] + md[1] + md[2] + md[3]) * (1.0f / 4096.0f));
}

}  // namespace

extern "C" void kernel_launch(void* const* d_in, const int* in_sizes, int n_in,
                              void* d_out, int out_size, void* d_ws,
                              size_t ws_size, hipStream_t stream) {
  (void)in_sizes; (void)n_in; (void)out_size; (void)ws_size;
  const float* x_start = (const float*)d_in[0];
  const float* x_end = (const float*)d_in[1];
  const float* noise = (const float*)d_in[2];
  const float* W1 = (const float*)d_in[3];
  const float* b1 = (const float*)d_in[4];
  const float* W2 = (const float*)d_in[5];
  const float* b2 = (const float*)d_in[6];
  const float* Ww1 = (const float*)d_in[7];
  const float* bw1 = (const float*)d_in[8];
  const float* Ww2 = (const float*)d_in[9];
  const float* bw2 = (const float*)d_in[10];
  const float* Wp1 = (const float*)d_in[11];
  const float* bp1 = (const float*)d_in[12];
  const float* wp2 = (const float*)d_in[13];
  float* out = (float*)d_out;

  // workspace layout (~66 MB)
  float* Xf = (float*)d_ws;                        // z_s      4096*256 f32
  float* ZEf = Xf + (size_t)4096 * 256;            // z_e
  float* Vf = ZEf + (size_t)4096 * 256;            // W_start
  short* Xb = (short*)(Vf + (size_t)4096 * 256);   // z_s bf16 4096*256
  short* HWb = Xb + (size_t)4096 * 256;            // wind hidden bf16
  short* XSb = HWb + (size_t)4096 * 256;           // x bf16   8192*2048
  short* H1b = XSb + (size_t)8192 * 2048;          // enc hidden bf16 8192*1024
  short* W1T = H1b + (size_t)8192 * 1024;          // 1024*2048
  short* W2T = W1T + (size_t)1024 * 2048;          // 256*1024
  short* Ww1T = W2T + (size_t)256 * 1024;
  short* Ww2T = Ww1T + 65536;
  short* WpT = Ww2T + 65536;                       // Wp1^T
  short* Wp1b = WpT + 65536;                       // Wp1 row-major

  const dim3 blk(256);

  cvt_t<<<dim3(32, 64), blk, 0, stream>>>(W1, W1T, 2048, 1024);
  cvt_t<<<dim3(8, 32), blk, 0, stream>>>(W2, W2T, 1024, 256);
  cvt4<<<dim3(8, 8, 4), blk, 0, stream>>>(Ww1, Ww2, Wp1, Ww1T, Ww2T, WpT,
                                          Wp1b);
  // fused z_s/z_e encoder: rows 0-4095 = x_start, 4096-8191 = x_end
  cvt2<<<2048, blk, 0, stream>>>(x_start, x_end, XSb, (long)8192 * 2048);
  gemm128<EPI_TANH><<<dim3(8, 64), blk, 0, stream>>>(
      XSb, W1T, b1, nullptr, H1b, 8192, 1024, 2048);
  gemm64<EPI_ENC2><<<dim3(4, 128), blk, 0, stream>>>(
      H1b, W2T, b2, Xf, Xb, ZEf, 8192, 256, 1024);
  // W_start = wind(z_s)
  gemm64<EPI_TANH><<<dim3(4, 64), blk, 0, stream>>>(
      Xb, Ww1T, bw1, nullptr, HWb, nullptr, 4096, 256, 256);
  gemm64<EPI_F32><<<dim3(4, 64), blk, 0, stream>>>(
      HWb, Ww2T, bw2, Vf, nullptr, nullptr, 4096, 256, 256);
  init_fb<<<1024, blk, 0, stream>>>(Vf, noise);

  hipMemsetAsync(d_out, 0, sizeof(float), stream);
  trace_fused<<<256, dim3(512), 0, stream>>>(Xf, Vf, ZEf, WpT, Wp1b, bp1, wp2,
                                             out);
}